// Round 1
// baseline (168.871 us; speedup 1.0000x reference)
//
#include <hip/hip_runtime.h>
#include <hip/hip_bf16.h>

typedef unsigned short u16;
typedef unsigned int u32;
typedef short bf16x8 __attribute__((ext_vector_type(8)));
typedef float f32x4 __attribute__((ext_vector_type(4)));

#define N_TOK 4096
#define C_DIM 256
#define HEADS 8
#define HD 32
#define SCALE_F 0.17677669529663687f   /* 32^-0.5 */

__device__ inline u16 f2bf(float f) {
    u32 u = __float_as_uint(f);
    u += 0x7fffu + ((u >> 16) & 1u);
    return (u16)(u >> 16);
}

__device__ inline void gload16(const void* g, void* l) {
    __builtin_amdgcn_global_load_lds((const __attribute__((address_space(1))) u32*)g,
                                     (__attribute__((address_space(3))) u32*)l, 16, 0, 0);
}

// ---------------- weight fp32 -> bf16 ----------------
__global__ __launch_bounds__(256) void conv_w(const float* __restrict__ w1, const float* __restrict__ w2,
                                              u16* __restrict__ o1, u16* __restrict__ o2) {
    int i = blockIdx.x * 256 + threadIdx.x;
    if (i < 1024 * 256) o1[i] = f2bf(w1[i]);
    if (i < 256 * 256)  o2[i] = f2bf(w2[i]);
}

// ---------------- x[b][c][l] fp32 -> xT[b][l][c] bf16 ----------------
__global__ __launch_bounds__(256) void transpose_x(const float* __restrict__ x, u16* __restrict__ xT) {
    int b = blockIdx.z;
    int c0 = blockIdx.y * 32, l0 = blockIdx.x * 32;
    const float* xb = x + ((size_t)b * C_DIM + c0) * N_TOK + l0;
    __shared__ u16 tl[32][33];
    int t = threadIdx.x;
    int li = t & 31, ci = t >> 5;
#pragma unroll
    for (int i = 0; i < 4; ++i)
        tl[ci + i * 8][li] = f2bf(xb[(size_t)(ci + i * 8) * N_TOK + li]);
    __syncthreads();
    int c2 = t & 15, lr = t >> 4;
    u16* outp = xT + ((size_t)b * N_TOK + l0) * C_DIM + c0;
#pragma unroll
    for (int i = 0; i < 2; ++i) {
        int l = lr + i * 16;
        u32 pv = (u32)tl[2 * c2][l] | ((u32)tl[2 * c2 + 1][l] << 16);
        *(u32*)(outp + (size_t)l * C_DIM + 2 * c2) = pv;
    }
}

// ---------------- bf16 MFMA GEMM:  C[b][m][l] = sum_k A[m][k]*B[b][l][k] + bias[m] ----------------
// A: [M][K] bf16 row-major; B: [L][K] bf16 per batch; C fp32.
__global__ __launch_bounds__(256) void gemm_bt(const u16* __restrict__ A, const u16* __restrict__ Bm,
                                               const float* __restrict__ bias, float* __restrict__ C,
                                               int M, int L, int K) {
    int bt = blockIdx.z;
    int m0 = blockIdx.y * 128;
    int l0 = blockIdx.x * 128;
    const u16* Bb = Bm + (size_t)bt * L * K;
    float* Cb = C + (size_t)bt * M * L;

    __shared__ u16 As[128 * 32];
    __shared__ u16 Bs[128 * 32];

    int t = threadIdx.x;
    int wv = t >> 6, lane = t & 63;
    int wr = (wv >> 1) * 64, wc = (wv & 1) * 64;

    f32x4 acc[4][4] = {};

    for (int k0 = 0; k0 < K; k0 += 32) {
#pragma unroll
        for (int j = 0; j < 2; ++j) {
            int chunk = wv * 128 + j * 64 + lane;
            int row = chunk >> 2, ko = (chunk & 3) * 8;
            gload16(A + (size_t)(m0 + row) * K + k0 + ko, (u16*)As + (size_t)(wv * 128 + j * 64) * 8);
            gload16(Bb + (size_t)(l0 + row) * K + k0 + ko, (u16*)Bs + (size_t)(wv * 128 + j * 64) * 8);
        }
        __syncthreads();
        int fr = lane & 15;
        int kg = (lane >> 4) * 8;
        bf16x8 af[4], bfr[4];
#pragma unroll
        for (int i = 0; i < 4; ++i) {
            af[i]  = *(const bf16x8*)(As + (size_t)(wr + i * 16 + fr) * 32 + kg);
            bfr[i] = *(const bf16x8*)(Bs + (size_t)(wc + i * 16 + fr) * 32 + kg);
        }
#pragma unroll
        for (int i = 0; i < 4; ++i)
#pragma unroll
            for (int jj = 0; jj < 4; ++jj)
                acc[i][jj] = __builtin_amdgcn_mfma_f32_16x16x32_bf16(af[i], bfr[jj], acc[i][jj], 0, 0, 0);
        __syncthreads();
    }

    int fr = lane & 15, rg = (lane >> 4) * 4;
#pragma unroll
    for (int i = 0; i < 4; ++i)
#pragma unroll
        for (int jj = 0; jj < 4; ++jj) {
            int col = l0 + wc + jj * 16 + fr;
#pragma unroll
            for (int r = 0; r < 4; ++r) {
                int row = m0 + wr + i * 16 + rg + r;
                Cb[(size_t)row * L + col] = acc[i][jj][r] + bias[row];
            }
        }
}

// ---------------- lepe: depthwise 5x5, pad 2, on v channels of qkvo ----------------
__global__ __launch_bounds__(256) void lepe_conv(const float* __restrict__ qkvo, const float* __restrict__ wl,
                                                 const float* __restrict__ bl, float* __restrict__ lepe) {
    int ht = blockIdx.x, c = blockIdx.y, b = blockIdx.z;
    const float* src = qkvo + ((size_t)b * 1024 + 512 + c) * N_TOK;
    float* dst = lepe + ((size_t)b * C_DIM + c) * N_TOK;
    __shared__ float tile[20][72];
    __shared__ float wcoef[25];
    int t = threadIdx.x;
    if (t < 25) wcoef[t] = wl[c * 25 + t];
    int h0 = ht * 16;
    for (int i = t; i < 20 * 72; i += 256) {
        int r = i / 72, cc = i % 72;
        int gh = h0 + r - 2, gw = cc - 4;
        float v = 0.f;
        if (gh >= 0 && gh < 64 && gw >= 0 && gw < 64) v = src[gh * 64 + gw];
        tile[r][cc] = v;
    }
    __syncthreads();
    int wq = t & 15, hh = t >> 4;
    int w0 = wq * 4;
    float bb = bl[c];
    float acc[4] = {bb, bb, bb, bb};
#pragma unroll
    for (int i = 0; i < 5; ++i) {
        const float* rowp = &tile[hh + i][0];
        float4 a0 = *(const float4*)(rowp + w0);
        float4 a1 = *(const float4*)(rowp + w0 + 4);
        float4 a2 = *(const float4*)(rowp + w0 + 8);
        float f[12] = {a0.x, a0.y, a0.z, a0.w, a1.x, a1.y, a1.z, a1.w, a2.x, a2.y, a2.z, a2.w};
#pragma unroll
        for (int jj = 0; jj < 5; ++jj) {
            float wv_ = wcoef[i * 5 + jj];
#pragma unroll
            for (int ow = 0; ow < 4; ++ow)
                acc[ow] += f[ow + jj + 2] * wv_;
        }
    }
    int h = h0 + hh;
#pragma unroll
    for (int ow = 0; ow < 4; ++ow) dst[h * 64 + w0 + ow] = acc[ow];
}

// ---------------- kv reduction: per (b,n) k'=elu+1(k); ksum; theta-shift; kv += ks^T v; vsum ----------------
__global__ __launch_bounds__(256) void kv_reduce(const float* __restrict__ qkvo, const float* __restrict__ sinp,
                                                 const float* __restrict__ cosp, float* __restrict__ part_kv,
                                                 float* __restrict__ part_ks, float* __restrict__ part_vs) {
    int chunk = blockIdx.x, bn = blockIdx.y;
    int b = bn >> 3, n = bn & 7;
    const float* kp = qkvo + ((size_t)b * 1024 + 256 + n * HD) * N_TOK;
    const float* vp = qkvo + ((size_t)b * 1024 + 512 + n * HD) * N_TOK;
    int lbase = chunk * 512;

    __shared__ float ks_lds[32][68];
    __shared__ float v_lds[32][68];
    __shared__ float red[64][33];

    int t = threadIdx.x;
    int lane6 = t & 63, grp = t >> 6;
    int slot = t & 63, lq = t >> 6;
    int d0 = (slot >> 3) * 4, e0 = (slot & 7) * 4;
    float acc[4][4] = {};
    float ksum_p[8] = {};
    float vsum_p[8] = {};

    for (int st = 0; st < 8; ++st) {
        int l0 = lbase + st * 64;
        __syncthreads();
#pragma unroll
        for (int i = 0; i < 8; ++i) {
            int idx = i * 256 + t;
            int d = idx >> 6, l = idx & 63;
            float kvl = kp[(size_t)d * N_TOK + l0 + l];
            float kp1 = kvl > 0.f ? kvl + 1.f : __expf(kvl);
            ks_lds[d][l] = kp1;
            ksum_p[i] += kp1;
            float vv = vp[(size_t)d * N_TOK + l0 + l];
            v_lds[d][l] = vv;
            vsum_p[i] += vv;
        }
        __syncthreads();
        // theta shift in place (each thread rewrites exactly what it read)
#pragma unroll
        for (int j = 0; j < 4; ++j) {
            int p = grp + 4 * j;
            float a  = ks_lds[2 * p][lane6];
            float bb = ks_lds[2 * p + 1][lane6];
            int l = l0 + lane6;
            float2 s2 = *(const float2*)(sinp + (size_t)l * HD + 2 * p);
            float2 c2 = *(const float2*)(cosp + (size_t)l * HD + 2 * p);
            ks_lds[2 * p][lane6]     = a * c2.x - bb * s2.x;
            ks_lds[2 * p + 1][lane6] = bb * c2.y + a * s2.y;
        }
        __syncthreads();
#pragma unroll
        for (int lt = 0; lt < 4; ++lt) {
            int ll = lq * 16 + lt * 4;
            float4 kf[4], vf[4];
#pragma unroll
            for (int i = 0; i < 4; ++i) {
                kf[i] = *(const float4*)&ks_lds[d0 + i][ll];
                vf[i] = *(const float4*)&v_lds[e0 + i][ll];
            }
#pragma unroll
            for (int i = 0; i < 4; ++i)
#pragma unroll
                for (int jj = 0; jj < 4; ++jj)
                    acc[i][jj] += kf[i].x * vf[jj].x + kf[i].y * vf[jj].y +
                                  kf[i].z * vf[jj].z + kf[i].w * vf[jj].w;
        }
    }
    float* pkv = part_kv + ((size_t)bn * 32 + chunk * 4 + lq) * 1024;
#pragma unroll
    for (int i = 0; i < 4; ++i)
#pragma unroll
        for (int jj = 0; jj < 4; ++jj)
            pkv[(d0 + i) * 32 + e0 + jj] = acc[i][jj];
    __syncthreads();
#pragma unroll
    for (int i = 0; i < 8; ++i) red[lane6][4 * i + grp] = ksum_p[i];
    __syncthreads();
    if (t < 32) {
        float s = 0;
        for (int l = 0; l < 64; ++l) s += red[l][t];
        part_ks[((size_t)bn * 8 + chunk) * 32 + t] = s;
    }
    __syncthreads();
#pragma unroll
    for (int i = 0; i < 8; ++i) red[lane6][4 * i + grp] = vsum_p[i];
    __syncthreads();
    if (t < 32) {
        float s = 0;
        for (int l = 0; l < 64; ++l) s += red[l][t];
        part_vs[((size_t)bn * 8 + chunk) * 32 + t] = s;
    }
}

__global__ __launch_bounds__(256) void kv_final(const float* __restrict__ part_kv, const float* __restrict__ part_ks,
                                                const float* __restrict__ part_vs, float* __restrict__ kv_fin,
                                                float* __restrict__ kmean, float* __restrict__ vmean) {
    int bn = blockIdx.x;
    int t = threadIdx.x;
    const float* p = part_kv + (size_t)bn * 32 * 1024;
    const float s2c = SCALE_F / (float)N_TOK;
#pragma unroll
    for (int i = 0; i < 4; ++i) {
        int sl = t + i * 256;
        float s = 0;
        for (int c = 0; c < 32; ++c) s += p[(size_t)c * 1024 + sl];
        kv_fin[(size_t)bn * 1024 + sl] = s * s2c;
    }
    if (t < 32) {
        float s = 0, sv = 0;
        for (int c = 0; c < 8; ++c) {
            s  += part_ks[((size_t)bn * 8 + c) * 32 + t];
            sv += part_vs[((size_t)bn * 8 + c) * 32 + t];
        }
        kmean[bn * 32 + t] = s * (1.f / (float)N_TOK);
        vmean[bn * 32 + t] = sv * (1.f / (float)N_TOK);
    }
}

// ---------------- attention epilogue -> resnT[b][l][c] bf16 ----------------
__global__ __launch_bounds__(256) void attn_epilogue(const float* __restrict__ qkvo, const float* __restrict__ sinp,
                                                     const float* __restrict__ cosp, const float* __restrict__ kv_fin,
                                                     const float* __restrict__ kmean, const float* __restrict__ vmean,
                                                     const float* __restrict__ lepe, u16* __restrict__ resnT) {
    int lt = blockIdx.x, bn = blockIdx.y;
    int b = bn >> 3, n = bn & 7;
    const float* qp = qkvo + ((size_t)b * 1024 + n * HD) * N_TOK;
    const float* op = qkvo + ((size_t)b * 1024 + 768 + n * HD) * N_TOK;
    const float* lp = lepe + ((size_t)b * C_DIM + n * HD) * N_TOK;

    __shared__ float kvl[1024];
    __shared__ float kml[32], vml[32];
    int t = threadIdx.x;
#pragma unroll
    for (int i = 0; i < 4; ++i) kvl[i * 256 + t] = kv_fin[(size_t)bn * 1024 + i * 256 + t];
    if (t < 32) { kml[t] = kmean[bn * 32 + t]; vml[t] = vmean[bn * 32 + t]; }
    __syncthreads();

    int l = lt * 256 + t;
    float qv[32];
    float z = 0.f;
#pragma unroll
    for (int d = 0; d < 32; ++d) {
        float x_ = qp[(size_t)d * N_TOK + l];
        float e_ = x_ > 0.f ? x_ + 1.f : __expf(x_);
        qv[d] = e_;
        z += e_ * kml[d];
    }
    z *= SCALE_F;
#pragma unroll
    for (int p = 0; p < 16; ++p) {
        float2 s2 = *(const float2*)(sinp + (size_t)l * HD + 2 * p);
        float2 c2 = *(const float2*)(cosp + (size_t)l * HD + 2 * p);
        float a = qv[2 * p], bb = qv[2 * p + 1];
        qv[2 * p]     = a * c2.x - bb * s2.x;
        qv[2 * p + 1] = bb * c2.y + a * s2.y;
    }
    float mult = 1.f + 1.f / (z + 1e-6f);

    float r[32];
#pragma unroll
    for (int eg = 0; eg < 8; ++eg) {
        float ax = 0, ay = 0, az = 0, aw = 0;
#pragma unroll
        for (int d = 0; d < 32; ++d) {
            float4 kvv = *(const float4*)&kvl[d * 32 + eg * 4];
            float qd = qv[d];
            ax += qd * kvv.x; ay += qd * kvv.y; az += qd * kvv.z; aw += qd * kvv.w;
        }
        r[eg * 4] = ax; r[eg * 4 + 1] = ay; r[eg * 4 + 2] = az; r[eg * 4 + 3] = aw;
    }

    u16* dstp = resnT + ((size_t)b * N_TOK + l) * C_DIM + n * HD;
#pragma unroll
    for (int g = 0; g < 4; ++g) {
        float vv[8];
#pragma unroll
        for (int e = 0; e < 8; ++e) {
            int ee = g * 8 + e;
            float res = r[ee] * mult - z * vml[ee];
            vv[e] = (res + lp[(size_t)ee * N_TOK + l]) * op[(size_t)ee * N_TOK + l];
        }
        uint4 u;
        u.x = (u32)f2bf(vv[0]) | ((u32)f2bf(vv[1]) << 16);
        u.y = (u32)f2bf(vv[2]) | ((u32)f2bf(vv[3]) << 16);
        u.z = (u32)f2bf(vv[4]) | ((u32)f2bf(vv[5]) << 16);
        u.w = (u32)f2bf(vv[6]) | ((u32)f2bf(vv[7]) << 16);
        ((uint4*)dstp)[g] = u;
    }
}

extern "C" void kernel_launch(void* const* d_in, const int* in_sizes, int n_in,
                              void* d_out, int out_size, void* d_ws, size_t ws_size,
                              hipStream_t stream) {
    const float* x      = (const float*)d_in[0];
    const float* sinp   = (const float*)d_in[1];
    const float* cosp   = (const float*)d_in[2];
    const float* w_qkvo = (const float*)d_in[3];
    const float* b_qkvo = (const float*)d_in[4];
    const float* w_lepe = (const float*)d_in[5];
    const float* b_lepe = (const float*)d_in[6];
    const float* w_proj = (const float*)d_in[7];
    const float* b_proj = (const float*)d_in[8];

    char* ws = (char*)d_ws;
    size_t off = 0;
    auto alloc = [&](size_t bytes) { size_t o = off; off = (off + bytes + 255) & ~(size_t)255; return o; };
    u16*   wbf     = (u16*)(ws + alloc((size_t)1024 * 256 * 2));
    u16*   wpbf    = (u16*)(ws + alloc((size_t)256 * 256 * 2));
    u16*   xT      = (u16*)(ws + alloc((size_t)8 * 4096 * 256 * 2));
    float* qkvo    = (float*)(ws + alloc((size_t)8 * 1024 * 4096 * 4));
    float* lepe    = (float*)(ws + alloc((size_t)8 * 256 * 4096 * 4));
    u16*   resnT   = (u16*)(ws + alloc((size_t)8 * 4096 * 256 * 2));
    float* part_kv = (float*)(ws + alloc((size_t)64 * 32 * 1024 * 4));
    float* part_ks = (float*)(ws + alloc((size_t)64 * 8 * 32 * 4));
    float* part_vs = (float*)(ws + alloc((size_t)64 * 8 * 32 * 4));
    float* kv_fin  = (float*)(ws + alloc((size_t)64 * 1024 * 4));
    float* kmean   = (float*)(ws + alloc((size_t)64 * 32 * 4));
    float* vmean   = (float*)(ws + alloc((size_t)64 * 32 * 4));
    if (off > ws_size) return;  // insufficient workspace -> loud validation failure

    conv_w<<<dim3(1024), dim3(256), 0, stream>>>(w_qkvo, w_proj, wbf, wpbf);
    transpose_x<<<dim3(128, 8, 8), dim3(256), 0, stream>>>(x, xT);
    gemm_bt<<<dim3(32, 8, 8), dim3(256), 0, stream>>>(wbf, xT, b_qkvo, qkvo, 1024, 4096, 256);
    lepe_conv<<<dim3(4, 256, 8), dim3(256), 0, stream>>>(qkvo, w_lepe, b_lepe, lepe);
    kv_reduce<<<dim3(8, 64), dim3(256), 0, stream>>>(qkvo, sinp, cosp, part_kv, part_ks, part_vs);
    kv_final<<<dim3(64), dim3(256), 0, stream>>>(part_kv, part_ks, part_vs, kv_fin, kmean, vmean);
    attn_epilogue<<<dim3(16, 64), dim3(256), 0, stream>>>(qkvo, sinp, cosp, kv_fin, kmean, vmean, lepe, resnT);
    gemm_bt<<<dim3(32, 2, 8), dim3(256), 0, stream>>>(wpbf, resnT, b_proj, (float*)d_out, 256, 4096, 256);
}

// Round 2
// 159.451 us; speedup vs baseline: 1.0591x; 1.0591x over previous
//
#include <hip/hip_runtime.h>
#include <hip/hip_bf16.h>

typedef unsigned short u16;
typedef unsigned int u32;
typedef short bf16x8 __attribute__((ext_vector_type(8)));
typedef float f32x4 __attribute__((ext_vector_type(4)));

#define N_TOK 4096
#define C_DIM 256
#define HEADS 8
#define HD 32
#define SCALE_F 0.17677669529663687f   /* 32^-0.5 */

__device__ inline u16 f2bf(float f) {
    u32 u = __float_as_uint(f);
    u += 0x7fffu + ((u >> 16) & 1u);
    return (u16)(u >> 16);
}
__device__ inline float bfbits_lo(u32 pair) { return __uint_as_float(pair << 16); }
__device__ inline float bfbits_hi(u32 pair) { return __uint_as_float(pair & 0xffff0000u); }

__device__ inline void gload16(const void* g, void* l) {
    __builtin_amdgcn_global_load_lds((const __attribute__((address_space(1))) u32*)g,
                                     (__attribute__((address_space(3))) u32*)l, 16, 0, 0);
}

// ---------------- weight fp32 -> bf16 ----------------
__global__ __launch_bounds__(256) void conv_w(const float* __restrict__ w1, const float* __restrict__ w2,
                                              u16* __restrict__ o1, u16* __restrict__ o2) {
    int i = blockIdx.x * 256 + threadIdx.x;
    if (i < 1024 * 256) o1[i] = f2bf(w1[i]);
    if (i < 256 * 256)  o2[i] = f2bf(w2[i]);
}

// ---------------- sin/cos [4096][32] -> [32][4096] ----------------
__global__ __launch_bounds__(256) void transpose_sc(const float* __restrict__ s, const float* __restrict__ c,
                                                    float* __restrict__ sT, float* __restrict__ cT) {
    int l0 = blockIdx.x * 64;
    const float* src = blockIdx.y ? c : s;
    float* dst = blockIdx.y ? cT : sT;
    __shared__ float tl[64][33];
    int t = threadIdx.x;
    int d = t & 31, r = t >> 5;
#pragma unroll
    for (int i = 0; i < 8; ++i) tl[r + i * 8][d] = src[(size_t)(l0 + r + i * 8) * HD + d];
    __syncthreads();
    int li = t & 63, dr = t >> 6;
#pragma unroll
    for (int i = 0; i < 8; ++i) dst[(size_t)(dr + i * 4) * N_TOK + l0 + li] = tl[li][dr + i * 4];
}

// ---------------- x[b][c][l] fp32 -> xT[b][l][c] bf16 ----------------
__global__ __launch_bounds__(256) void transpose_x(const float* __restrict__ x, u16* __restrict__ xT) {
    int b = blockIdx.z;
    int c0 = blockIdx.y * 32, l0 = blockIdx.x * 32;
    const float* xb = x + ((size_t)b * C_DIM + c0) * N_TOK + l0;
    __shared__ u16 tl[32][33];
    int t = threadIdx.x;
    int li = t & 31, ci = t >> 5;
#pragma unroll
    for (int i = 0; i < 4; ++i)
        tl[ci + i * 8][li] = f2bf(xb[(size_t)(ci + i * 8) * N_TOK + li]);
    __syncthreads();
    int c2 = t & 15, lr = t >> 4;
    u16* outp = xT + ((size_t)b * N_TOK + l0) * C_DIM + c0;
#pragma unroll
    for (int i = 0; i < 2; ++i) {
        int l = lr + i * 16;
        u32 pv = (u32)tl[2 * c2][l] | ((u32)tl[2 * c2 + 1][l] << 16);
        *(u32*)(outp + (size_t)l * C_DIM + 2 * c2) = pv;
    }
}

// ---------------- bf16 MFMA GEMM:  C[b][m][l] = sum_k A[m][k]*B[b][l][k] + bias[m] ----------------
__global__ __launch_bounds__(256) void gemm_bt(const u16* __restrict__ A, const u16* __restrict__ Bm,
                                               const float* __restrict__ bias, float* __restrict__ C,
                                               int M, int L, int K) {
    int bt = blockIdx.z;
    int m0 = blockIdx.y * 128;
    int l0 = blockIdx.x * 128;
    const u16* Bb = Bm + (size_t)bt * L * K;
    float* Cb = C + (size_t)bt * M * L;

    __shared__ u16 As[128 * 32];
    __shared__ u16 Bs[128 * 32];

    int t = threadIdx.x;
    int wv = t >> 6, lane = t & 63;
    int wr = (wv >> 1) * 64, wc = (wv & 1) * 64;

    f32x4 acc[4][4] = {};

    for (int k0 = 0; k0 < K; k0 += 32) {
#pragma unroll
        for (int j = 0; j < 2; ++j) {
            int chunk = wv * 128 + j * 64 + lane;
            int row = chunk >> 2, ko = (chunk & 3) * 8;
            gload16(A + (size_t)(m0 + row) * K + k0 + ko, (u16*)As + (size_t)(wv * 128 + j * 64) * 8);
            gload16(Bb + (size_t)(l0 + row) * K + k0 + ko, (u16*)Bs + (size_t)(wv * 128 + j * 64) * 8);
        }
        __syncthreads();
        int fr = lane & 15;
        int kg = (lane >> 4) * 8;
        bf16x8 af[4], bfr[4];
#pragma unroll
        for (int i = 0; i < 4; ++i) {
            af[i]  = *(const bf16x8*)(As + (size_t)(wr + i * 16 + fr) * 32 + kg);
            bfr[i] = *(const bf16x8*)(Bs + (size_t)(wc + i * 16 + fr) * 32 + kg);
        }
#pragma unroll
        for (int i = 0; i < 4; ++i)
#pragma unroll
            for (int jj = 0; jj < 4; ++jj)
                acc[i][jj] = __builtin_amdgcn_mfma_f32_16x16x32_bf16(af[i], bfr[jj], acc[i][jj], 0, 0, 0);
        __syncthreads();
    }

    int fr = lane & 15, rg = (lane >> 4) * 4;
#pragma unroll
    for (int i = 0; i < 4; ++i)
#pragma unroll
        for (int jj = 0; jj < 4; ++jj) {
            int col = l0 + wc + jj * 16 + fr;
#pragma unroll
            for (int r = 0; r < 4; ++r) {
                int row = m0 + wr + i * 16 + rg + r;
                Cb[(size_t)row * L + col] = acc[i][jj][r] + bias[row];
            }
        }
}

// ---------------- lepe: depthwise 5x5, pad 2, on v channels of qkvo -> bf16 ----------------
__global__ __launch_bounds__(256) void lepe_conv(const float* __restrict__ qkvo, const float* __restrict__ wl,
                                                 const float* __restrict__ bl, u16* __restrict__ lepe) {
    int ht = blockIdx.x, c = blockIdx.y, b = blockIdx.z;
    const float* src = qkvo + ((size_t)b * 1024 + 512 + c) * N_TOK;
    u16* dst = lepe + ((size_t)b * C_DIM + c) * N_TOK;
    __shared__ float tile[20][72];
    __shared__ float wcoef[25];
    int t = threadIdx.x;
    if (t < 25) wcoef[t] = wl[c * 25 + t];
    int h0 = ht * 16;
    for (int i = t; i < 20 * 72; i += 256) {
        int r = i / 72, cc = i % 72;
        int gh = h0 + r - 2, gw = cc - 4;
        float v = 0.f;
        if (gh >= 0 && gh < 64 && gw >= 0 && gw < 64) v = src[gh * 64 + gw];
        tile[r][cc] = v;
    }
    __syncthreads();
    int wq = t & 15, hh = t >> 4;
    int w0 = wq * 4;
    float bb = bl[c];
    float acc[4] = {bb, bb, bb, bb};
#pragma unroll
    for (int i = 0; i < 5; ++i) {
        const float* rowp = &tile[hh + i][0];
        float4 a0 = *(const float4*)(rowp + w0);
        float4 a1 = *(const float4*)(rowp + w0 + 4);
        float4 a2 = *(const float4*)(rowp + w0 + 8);
        float f[12] = {a0.x, a0.y, a0.z, a0.w, a1.x, a1.y, a1.z, a1.w, a2.x, a2.y, a2.z, a2.w};
#pragma unroll
        for (int jj = 0; jj < 5; ++jj) {
            float wv_ = wcoef[i * 5 + jj];
#pragma unroll
            for (int ow = 0; ow < 4; ++ow)
                acc[ow] += f[ow + jj + 2] * wv_;
        }
    }
    int h = h0 + hh;
    uint2 pv;
    pv.x = (u32)f2bf(acc[0]) | ((u32)f2bf(acc[1]) << 16);
    pv.y = (u32)f2bf(acc[2]) | ((u32)f2bf(acc[3]) << 16);
    *(uint2*)(dst + h * 64 + w0) = pv;
}

// ---------------- kv reduction ----------------
__global__ __launch_bounds__(256) void kv_reduce(const float* __restrict__ qkvo, const float* __restrict__ sinT,
                                                 const float* __restrict__ cosT, float* __restrict__ part_kv,
                                                 float* __restrict__ part_ks, float* __restrict__ part_vs) {
    int chunk = blockIdx.x, bn = blockIdx.y;
    int b = bn >> 3, n = bn & 7;
    const float* kp = qkvo + ((size_t)b * 1024 + 256 + n * HD) * N_TOK;
    const float* vp = qkvo + ((size_t)b * 1024 + 512 + n * HD) * N_TOK;
    int lbase = chunk * 512;

    __shared__ float ks_lds[32][68];
    __shared__ float v_lds[32][68];
    __shared__ float red[64][33];

    int t = threadIdx.x;
    int lane6 = t & 63, grp = t >> 6;
    int slot = t & 63, lq = t >> 6;
    int d0 = (slot >> 3) * 4, e0 = (slot & 7) * 4;
    float acc[4][4] = {};
    float ksum_p[8] = {};
    float vsum_p[8] = {};

    for (int st = 0; st < 8; ++st) {
        int l0 = lbase + st * 64;
        __syncthreads();
#pragma unroll
        for (int i = 0; i < 8; ++i) {
            int idx = i * 256 + t;
            int d = idx >> 6, l = idx & 63;
            float kvl = kp[(size_t)d * N_TOK + l0 + l];
            float kp1 = kvl > 0.f ? kvl + 1.f : __expf(kvl);
            ks_lds[d][l] = kp1;
            ksum_p[i] += kp1;
            float vv = vp[(size_t)d * N_TOK + l0 + l];
            v_lds[d][l] = vv;
            vsum_p[i] += vv;
        }
        __syncthreads();
        // theta shift in place; sin/cos from transposed tables (coalesced in l)
#pragma unroll
        for (int j = 0; j < 4; ++j) {
            int p = grp + 4 * j;
            float a  = ks_lds[2 * p][lane6];
            float bb = ks_lds[2 * p + 1][lane6];
            int l = l0 + lane6;
            float se = sinT[(size_t)(2 * p) * N_TOK + l];
            float so = sinT[(size_t)(2 * p + 1) * N_TOK + l];
            float ce = cosT[(size_t)(2 * p) * N_TOK + l];
            float co = cosT[(size_t)(2 * p + 1) * N_TOK + l];
            ks_lds[2 * p][lane6]     = a * ce - bb * se;
            ks_lds[2 * p + 1][lane6] = bb * co + a * so;
        }
        __syncthreads();
#pragma unroll
        for (int lt = 0; lt < 4; ++lt) {
            int ll = lq * 16 + lt * 4;
            float4 kf[4], vf[4];
#pragma unroll
            for (int i = 0; i < 4; ++i) {
                kf[i] = *(const float4*)&ks_lds[d0 + i][ll];
                vf[i] = *(const float4*)&v_lds[e0 + i][ll];
            }
#pragma unroll
            for (int i = 0; i < 4; ++i)
#pragma unroll
                for (int jj = 0; jj < 4; ++jj)
                    acc[i][jj] += kf[i].x * vf[jj].x + kf[i].y * vf[jj].y +
                                  kf[i].z * vf[jj].z + kf[i].w * vf[jj].w;
        }
    }
    float* pkv = part_kv + ((size_t)bn * 32 + chunk * 4 + lq) * 1024;
#pragma unroll
    for (int i = 0; i < 4; ++i)
#pragma unroll
        for (int jj = 0; jj < 4; ++jj)
            pkv[(d0 + i) * 32 + e0 + jj] = acc[i][jj];
    __syncthreads();
#pragma unroll
    for (int i = 0; i < 8; ++i) red[lane6][4 * i + grp] = ksum_p[i];
    __syncthreads();
    if (t < 32) {
        float s = 0;
        for (int l = 0; l < 64; ++l) s += red[l][t];
        part_ks[((size_t)bn * 8 + chunk) * 32 + t] = s;
    }
    __syncthreads();
#pragma unroll
    for (int i = 0; i < 8; ++i) red[lane6][4 * i + grp] = vsum_p[i];
    __syncthreads();
    if (t < 32) {
        float s = 0;
        for (int l = 0; l < 64; ++l) s += red[l][t];
        part_vs[((size_t)bn * 8 + chunk) * 32 + t] = s;
    }
}

__global__ __launch_bounds__(256) void kv_final(const float* __restrict__ part_kv, const float* __restrict__ part_ks,
                                                const float* __restrict__ part_vs, float* __restrict__ kv_fin,
                                                float* __restrict__ kmean, float* __restrict__ vmean) {
    int bn = blockIdx.x;
    int t = threadIdx.x;
    const float* p = part_kv + (size_t)bn * 32 * 1024;
    const float s2c = SCALE_F / (float)N_TOK;
#pragma unroll
    for (int i = 0; i < 4; ++i) {
        int sl = t + i * 256;
        float s = 0;
        for (int c = 0; c < 32; ++c) s += p[(size_t)c * 1024 + sl];
        kv_fin[(size_t)bn * 1024 + sl] = s * s2c;
    }
    if (t < 32) {
        float s = 0, sv = 0;
        for (int c = 0; c < 8; ++c) {
            s  += part_ks[((size_t)bn * 8 + c) * 32 + t];
            sv += part_vs[((size_t)bn * 8 + c) * 32 + t];
        }
        kmean[bn * 32 + t] = s * (1.f / (float)N_TOK);
        vmean[bn * 32 + t] = sv * (1.f / (float)N_TOK);
    }
}

// ---------------- attention epilogue, 2 tokens/thread -> resnT[b][l][c] bf16 ----------------
__global__ __launch_bounds__(256) void attn_epilogue(const float* __restrict__ qkvo, const float* __restrict__ sinT,
                                                     const float* __restrict__ cosT, const float* __restrict__ kv_fin,
                                                     const float* __restrict__ kmean, const float* __restrict__ vmean,
                                                     const u16* __restrict__ lepe, u16* __restrict__ resnT) {
    int lt = blockIdx.x, bn = blockIdx.y;
    int b = bn >> 3, n = bn & 7;
    const float* qp = qkvo + ((size_t)b * 1024 + n * HD) * N_TOK;
    const float* op = qkvo + ((size_t)b * 1024 + 768 + n * HD) * N_TOK;
    const u16* lp = lepe + ((size_t)b * C_DIM + n * HD) * N_TOK;

    __shared__ float kvl[1024];
    __shared__ float kml[32], vml[32];
    int t = threadIdx.x;
    ((f32x4*)kvl)[t] = ((const f32x4*)(kv_fin + (size_t)bn * 1024))[t];
    if (t < 32) { kml[t] = kmean[bn * 32 + t]; vml[t] = vmean[bn * 32 + t]; }
    __syncthreads();

    int l = lt * 512 + 2 * t;   // tokens l, l+1
    float2 qv[32];
    float zx = 0.f, zy = 0.f;
#pragma unroll
    for (int d = 0; d < 32; ++d) {
        float2 xv = *(const float2*)(qp + (size_t)d * N_TOK + l);
        float ex = xv.x > 0.f ? xv.x + 1.f : __expf(xv.x);
        float ey = xv.y > 0.f ? xv.y + 1.f : __expf(xv.y);
        qv[d].x = ex; qv[d].y = ey;
        zx += ex * kml[d]; zy += ey * kml[d];
    }
    zx *= SCALE_F; zy *= SCALE_F;
#pragma unroll
    for (int p = 0; p < 16; ++p) {
        float2 se = *(const float2*)(sinT + (size_t)(2 * p) * N_TOK + l);
        float2 so = *(const float2*)(sinT + (size_t)(2 * p + 1) * N_TOK + l);
        float2 ce = *(const float2*)(cosT + (size_t)(2 * p) * N_TOK + l);
        float2 co = *(const float2*)(cosT + (size_t)(2 * p + 1) * N_TOK + l);
        float2 a = qv[2 * p], bb = qv[2 * p + 1];
        qv[2 * p].x     = a.x * ce.x - bb.x * se.x;
        qv[2 * p].y     = a.y * ce.y - bb.y * se.y;
        qv[2 * p + 1].x = bb.x * co.x + a.x * so.x;
        qv[2 * p + 1].y = bb.y * co.y + a.y * so.y;
    }
    float multx = 1.f + 1.f / (zx + 1e-6f);
    float multy = 1.f + 1.f / (zy + 1e-6f);

    float2 r[32];
#pragma unroll
    for (int e = 0; e < 32; ++e) { r[e].x = 0.f; r[e].y = 0.f; }
#pragma unroll
    for (int d = 0; d < 32; ++d) {
        float2 qd = qv[d];
#pragma unroll
        for (int eg = 0; eg < 8; ++eg) {
            f32x4 kvv = *(const f32x4*)&kvl[d * 32 + eg * 4];
#pragma unroll
            for (int k = 0; k < 4; ++k) {
                r[eg * 4 + k].x += qd.x * kvv[k];
                r[eg * 4 + k].y += qd.y * kvv[k];
            }
        }
    }

    u16* dst0 = resnT + ((size_t)b * N_TOK + l) * C_DIM + n * HD;
#pragma unroll
    for (int g = 0; g < 4; ++g) {
        float vx[8], vy[8];
#pragma unroll
        for (int e2 = 0; e2 < 8; ++e2) {
            int ee = g * 8 + e2;
            u32 lpair = *(const u32*)(lp + (size_t)ee * N_TOK + l);
            float lx = bfbits_lo(lpair), ly = bfbits_hi(lpair);
            float2 ov = *(const float2*)(op + (size_t)ee * N_TOK + l);
            float rx = r[ee].x * multx - zx * vml[ee];
            float ry = r[ee].y * multy - zy * vml[ee];
            vx[e2] = (rx + lx) * ov.x;
            vy[e2] = (ry + ly) * ov.y;
        }
        uint4 ux, uy;
        ux.x = (u32)f2bf(vx[0]) | ((u32)f2bf(vx[1]) << 16);
        ux.y = (u32)f2bf(vx[2]) | ((u32)f2bf(vx[3]) << 16);
        ux.z = (u32)f2bf(vx[4]) | ((u32)f2bf(vx[5]) << 16);
        ux.w = (u32)f2bf(vx[6]) | ((u32)f2bf(vx[7]) << 16);
        uy.x = (u32)f2bf(vy[0]) | ((u32)f2bf(vy[1]) << 16);
        uy.y = (u32)f2bf(vy[2]) | ((u32)f2bf(vy[3]) << 16);
        uy.z = (u32)f2bf(vy[4]) | ((u32)f2bf(vy[5]) << 16);
        uy.w = (u32)f2bf(vy[6]) | ((u32)f2bf(vy[7]) << 16);
        ((uint4*)(dst0 + g * 8))[0] = ux;
        ((uint4*)(dst0 + C_DIM + g * 8))[0] = uy;
    }
}

extern "C" void kernel_launch(void* const* d_in, const int* in_sizes, int n_in,
                              void* d_out, int out_size, void* d_ws, size_t ws_size,
                              hipStream_t stream) {
    const float* x      = (const float*)d_in[0];
    const float* sinp   = (const float*)d_in[1];
    const float* cosp   = (const float*)d_in[2];
    const float* w_qkvo = (const float*)d_in[3];
    const float* b_qkvo = (const float*)d_in[4];
    const float* w_lepe = (const float*)d_in[5];
    const float* b_lepe = (const float*)d_in[6];
    const float* w_proj = (const float*)d_in[7];
    const float* b_proj = (const float*)d_in[8];

    char* ws = (char*)d_ws;
    size_t off = 0;
    auto alloc = [&](size_t bytes) { size_t o = off; off = (off + bytes + 255) & ~(size_t)255; return o; };
    u16*   wbf     = (u16*)(ws + alloc((size_t)1024 * 256 * 2));
    u16*   wpbf    = (u16*)(ws + alloc((size_t)256 * 256 * 2));
    u16*   xT      = (u16*)(ws + alloc((size_t)8 * 4096 * 256 * 2));
    float* qkvo    = (float*)(ws + alloc((size_t)8 * 1024 * 4096 * 4));
    u16*   lepe    = (u16*)(ws + alloc((size_t)8 * 256 * 4096 * 2));
    u16*   resnT   = (u16*)(ws + alloc((size_t)8 * 4096 * 256 * 2));
    float* part_kv = (float*)(ws + alloc((size_t)64 * 32 * 1024 * 4));
    float* part_ks = (float*)(ws + alloc((size_t)64 * 8 * 32 * 4));
    float* part_vs = (float*)(ws + alloc((size_t)64 * 8 * 32 * 4));
    float* kv_fin  = (float*)(ws + alloc((size_t)64 * 1024 * 4));
    float* kmean   = (float*)(ws + alloc((size_t)64 * 32 * 4));
    float* vmean   = (float*)(ws + alloc((size_t)64 * 32 * 4));
    float* sinT    = (float*)(ws + alloc((size_t)32 * 4096 * 4));
    float* cosT    = (float*)(ws + alloc((size_t)32 * 4096 * 4));
    if (off > ws_size) return;  // insufficient workspace -> loud validation failure

    conv_w<<<dim3(1024), dim3(256), 0, stream>>>(w_qkvo, w_proj, wbf, wpbf);
    transpose_sc<<<dim3(64, 2), dim3(256), 0, stream>>>(sinp, cosp, sinT, cosT);
    transpose_x<<<dim3(128, 8, 8), dim3(256), 0, stream>>>(x, xT);
    gemm_bt<<<dim3(32, 8, 8), dim3(256), 0, stream>>>(wbf, xT, b_qkvo, qkvo, 1024, 4096, 256);
    lepe_conv<<<dim3(4, 256, 8), dim3(256), 0, stream>>>(qkvo, w_lepe, b_lepe, lepe);
    kv_reduce<<<dim3(8, 64), dim3(256), 0, stream>>>(qkvo, sinT, cosT, part_kv, part_ks, part_vs);
    kv_final<<<dim3(64), dim3(256), 0, stream>>>(part_kv, part_ks, part_vs, kv_fin, kmean, vmean);
    attn_epilogue<<<dim3(8, 64), dim3(256), 0, stream>>>(qkvo, sinT, cosT, kv_fin, kmean, vmean, lepe, resnT);
    gemm_bt<<<dim3(32, 2, 8), dim3(256), 0, stream>>>(wpbf, resnT, b_proj, (float*)d_out, 256, 4096, 256);
}

// Round 3
// 147.881 us; speedup vs baseline: 1.1419x; 1.0782x over previous
//
#include <hip/hip_runtime.h>
#include <hip/hip_bf16.h>

typedef unsigned short u16;
typedef unsigned int u32;
typedef short bf16x8 __attribute__((ext_vector_type(8)));
typedef float f32x4 __attribute__((ext_vector_type(4)));

#define N_TOK 4096
#define C_DIM 256
#define HEADS 8
#define HD 32
#define SCALE_F 0.17677669529663687f   /* 32^-0.5 */

__device__ inline u16 f2bf(float f) {
    u32 u = __float_as_uint(f);
    u += 0x7fffu + ((u >> 16) & 1u);
    return (u16)(u >> 16);
}

__device__ inline void gload16(const void* g, void* l) {
    __builtin_amdgcn_global_load_lds((const __attribute__((address_space(1))) u32*)g,
                                     (__attribute__((address_space(3))) u32*)l, 16, 0, 0);
}

// ---------------- weight fp32 -> bf16 ----------------
__global__ __launch_bounds__(256) void conv_w(const float* __restrict__ w1, const float* __restrict__ w2,
                                              u16* __restrict__ o1, u16* __restrict__ o2) {
    int i = blockIdx.x * 256 + threadIdx.x;
    if (i < 1024 * 256) o1[i] = f2bf(w1[i]);
    if (i < 256 * 256)  o2[i] = f2bf(w2[i]);
}

// ---------------- sin/cos [4096][32] -> [32][4096] ----------------
__global__ __launch_bounds__(256) void transpose_sc(const float* __restrict__ s, const float* __restrict__ c,
                                                    float* __restrict__ sT, float* __restrict__ cT) {
    int l0 = blockIdx.x * 64;
    const float* src = blockIdx.y ? c : s;
    float* dst = blockIdx.y ? cT : sT;
    __shared__ float tl[64][33];
    int t = threadIdx.x;
    int d = t & 31, r = t >> 5;
#pragma unroll
    for (int i = 0; i < 8; ++i) tl[r + i * 8][d] = src[(size_t)(l0 + r + i * 8) * HD + d];
    __syncthreads();
    int li = t & 63, dr = t >> 6;
#pragma unroll
    for (int i = 0; i < 8; ++i) dst[(size_t)(dr + i * 4) * N_TOK + l0 + li] = tl[li][dr + i * 4];
}

// ---------------- x[b][c][l] fp32 -> xT[b][l][c] bf16 ----------------
__global__ __launch_bounds__(256) void transpose_x(const float* __restrict__ x, u16* __restrict__ xT) {
    int b = blockIdx.z;
    int c0 = blockIdx.y * 32, l0 = blockIdx.x * 32;
    const float* xb = x + ((size_t)b * C_DIM + c0) * N_TOK + l0;
    __shared__ u16 tl[32][33];
    int t = threadIdx.x;
    int li = t & 31, ci = t >> 5;
#pragma unroll
    for (int i = 0; i < 4; ++i)
        tl[ci + i * 8][li] = f2bf(xb[(size_t)(ci + i * 8) * N_TOK + li]);
    __syncthreads();
    int c2 = t & 15, lr = t >> 4;
    u16* outp = xT + ((size_t)b * N_TOK + l0) * C_DIM + c0;
#pragma unroll
    for (int i = 0; i < 2; ++i) {
        int l = lr + i * 16;
        u32 pv = (u32)tl[2 * c2][l] | ((u32)tl[2 * c2 + 1][l] << 16);
        *(u32*)(outp + (size_t)l * C_DIM + 2 * c2) = pv;
    }
}

// ---------------- bf16 MFMA GEMM:  C[b][m][l] = sum_k A[m][k]*B[b][l][k] + bias[m] ----------------
__global__ __launch_bounds__(256) void gemm_bt(const u16* __restrict__ A, const u16* __restrict__ Bm,
                                               const float* __restrict__ bias, float* __restrict__ C,
                                               int M, int L, int K) {
    int bt = blockIdx.z;
    int m0 = blockIdx.y * 128;
    int l0 = blockIdx.x * 128;
    const u16* Bb = Bm + (size_t)bt * L * K;
    float* Cb = C + (size_t)bt * M * L;

    __shared__ u16 As[128 * 32];
    __shared__ u16 Bs[128 * 32];

    int t = threadIdx.x;
    int wv = t >> 6, lane = t & 63;
    int wr = (wv >> 1) * 64, wc = (wv & 1) * 64;

    f32x4 acc[4][4] = {};

    for (int k0 = 0; k0 < K; k0 += 32) {
#pragma unroll
        for (int j = 0; j < 2; ++j) {
            int chunk = wv * 128 + j * 64 + lane;
            int row = chunk >> 2, ko = (chunk & 3) * 8;
            gload16(A + (size_t)(m0 + row) * K + k0 + ko, (u16*)As + (size_t)(wv * 128 + j * 64) * 8);
            gload16(Bb + (size_t)(l0 + row) * K + k0 + ko, (u16*)Bs + (size_t)(wv * 128 + j * 64) * 8);
        }
        __syncthreads();
        int fr = lane & 15;
        int kg = (lane >> 4) * 8;
        bf16x8 af[4], bfr[4];
#pragma unroll
        for (int i = 0; i < 4; ++i) {
            af[i]  = *(const bf16x8*)(As + (size_t)(wr + i * 16 + fr) * 32 + kg);
            bfr[i] = *(const bf16x8*)(Bs + (size_t)(wc + i * 16 + fr) * 32 + kg);
        }
#pragma unroll
        for (int i = 0; i < 4; ++i)
#pragma unroll
            for (int jj = 0; jj < 4; ++jj)
                acc[i][jj] = __builtin_amdgcn_mfma_f32_16x16x32_bf16(af[i], bfr[jj], acc[i][jj], 0, 0, 0);
        __syncthreads();
    }

    int fr = lane & 15, rg = (lane >> 4) * 4;
#pragma unroll
    for (int i = 0; i < 4; ++i)
#pragma unroll
        for (int jj = 0; jj < 4; ++jj) {
            int col = l0 + wc + jj * 16 + fr;
#pragma unroll
            for (int r = 0; r < 4; ++r) {
                int row = m0 + wr + i * 16 + rg + r;
                Cb[(size_t)row * L + col] = acc[i][jj][r] + bias[row];
            }
        }
}

// ---------------- lepe: depthwise 5x5, pad 2, on v channels of qkvo -> bf16 ----------------
__global__ __launch_bounds__(256) void lepe_conv(const float* __restrict__ qkvo, const float* __restrict__ wl,
                                                 const float* __restrict__ bl, u16* __restrict__ lepe) {
    int ht = blockIdx.x, c = blockIdx.y, b = blockIdx.z;
    const float* src = qkvo + ((size_t)b * 1024 + 512 + c) * N_TOK;
    u16* dst = lepe + ((size_t)b * C_DIM + c) * N_TOK;
    __shared__ float tile[20][72];
    __shared__ float wcoef[25];
    int t = threadIdx.x;
    if (t < 25) wcoef[t] = wl[c * 25 + t];
    int h0 = ht * 16;
    for (int i = t; i < 20 * 72; i += 256) {
        int r = i / 72, cc = i % 72;
        int gh = h0 + r - 2, gw = cc - 4;
        float v = 0.f;
        if (gh >= 0 && gh < 64 && gw >= 0 && gw < 64) v = src[gh * 64 + gw];
        tile[r][cc] = v;
    }
    __syncthreads();
    int wq = t & 15, hh = t >> 4;
    int w0 = wq * 4;
    float bb = bl[c];
    float acc[4] = {bb, bb, bb, bb};
#pragma unroll
    for (int i = 0; i < 5; ++i) {
        const float* rowp = &tile[hh + i][0];
        float4 a0 = *(const float4*)(rowp + w0);
        float4 a1 = *(const float4*)(rowp + w0 + 4);
        float4 a2 = *(const float4*)(rowp + w0 + 8);
        float f[12] = {a0.x, a0.y, a0.z, a0.w, a1.x, a1.y, a1.z, a1.w, a2.x, a2.y, a2.z, a2.w};
#pragma unroll
        for (int jj = 0; jj < 5; ++jj) {
            float wv_ = wcoef[i * 5 + jj];
#pragma unroll
            for (int ow = 0; ow < 4; ++ow)
                acc[ow] += f[ow + jj + 2] * wv_;
        }
    }
    int h = h0 + hh;
    uint2 pv;
    pv.x = (u32)f2bf(acc[0]) | ((u32)f2bf(acc[1]) << 16);
    pv.y = (u32)f2bf(acc[2]) | ((u32)f2bf(acc[3]) << 16);
    *(uint2*)(dst + h * 64 + w0) = pv;
}

// ---------------- kv reduction ----------------
__global__ __launch_bounds__(256) void kv_reduce(const float* __restrict__ qkvo, const float* __restrict__ sinT,
                                                 const float* __restrict__ cosT, float* __restrict__ part_kv,
                                                 float* __restrict__ part_ks, float* __restrict__ part_vs) {
    int chunk = blockIdx.x, bn = blockIdx.y;
    int b = bn >> 3, n = bn & 7;
    const float* kp = qkvo + ((size_t)b * 1024 + 256 + n * HD) * N_TOK;
    const float* vp = qkvo + ((size_t)b * 1024 + 512 + n * HD) * N_TOK;
    int lbase = chunk * 512;

    __shared__ float ks_lds[32][68];
    __shared__ float v_lds[32][68];
    __shared__ float red[64][33];

    int t = threadIdx.x;
    int lane6 = t & 63, grp = t >> 6;
    int slot = t & 63, lq = t >> 6;
    int d0 = (slot >> 3) * 4, e0 = (slot & 7) * 4;
    float acc[4][4] = {};
    float ksum_p[8] = {};
    float vsum_p[8] = {};

    for (int st = 0; st < 8; ++st) {
        int l0 = lbase + st * 64;
        __syncthreads();
#pragma unroll
        for (int i = 0; i < 8; ++i) {
            int idx = i * 256 + t;
            int d = idx >> 6, l = idx & 63;
            float kvl = kp[(size_t)d * N_TOK + l0 + l];
            float kp1 = kvl > 0.f ? kvl + 1.f : __expf(kvl);
            ks_lds[d][l] = kp1;
            ksum_p[i] += kp1;
            float vv = vp[(size_t)d * N_TOK + l0 + l];
            v_lds[d][l] = vv;
            vsum_p[i] += vv;
        }
        __syncthreads();
#pragma unroll
        for (int j = 0; j < 4; ++j) {
            int p = grp + 4 * j;
            float a  = ks_lds[2 * p][lane6];
            float bb = ks_lds[2 * p + 1][lane6];
            int l = l0 + lane6;
            float se = sinT[(size_t)(2 * p) * N_TOK + l];
            float so = sinT[(size_t)(2 * p + 1) * N_TOK + l];
            float ce = cosT[(size_t)(2 * p) * N_TOK + l];
            float co = cosT[(size_t)(2 * p + 1) * N_TOK + l];
            ks_lds[2 * p][lane6]     = a * ce - bb * se;
            ks_lds[2 * p + 1][lane6] = bb * co + a * so;
        }
        __syncthreads();
#pragma unroll
        for (int lt = 0; lt < 4; ++lt) {
            int ll = lq * 16 + lt * 4;
            float4 kf[4], vf[4];
#pragma unroll
            for (int i = 0; i < 4; ++i) {
                kf[i] = *(const float4*)&ks_lds[d0 + i][ll];
                vf[i] = *(const float4*)&v_lds[e0 + i][ll];
            }
#pragma unroll
            for (int i = 0; i < 4; ++i)
#pragma unroll
                for (int jj = 0; jj < 4; ++jj)
                    acc[i][jj] += kf[i].x * vf[jj].x + kf[i].y * vf[jj].y +
                                  kf[i].z * vf[jj].z + kf[i].w * vf[jj].w;
        }
    }
    float* pkv = part_kv + ((size_t)bn * 32 + chunk * 4 + lq) * 1024;
#pragma unroll
    for (int i = 0; i < 4; ++i)
#pragma unroll
        for (int jj = 0; jj < 4; ++jj)
            pkv[(d0 + i) * 32 + e0 + jj] = acc[i][jj];
    __syncthreads();
#pragma unroll
    for (int i = 0; i < 8; ++i) red[lane6][4 * i + grp] = ksum_p[i];
    __syncthreads();
    if (t < 32) {
        float s = 0;
        for (int l = 0; l < 64; ++l) s += red[l][t];
        part_ks[((size_t)bn * 8 + chunk) * 32 + t] = s;
    }
    __syncthreads();
#pragma unroll
    for (int i = 0; i < 8; ++i) red[lane6][4 * i + grp] = vsum_p[i];
    __syncthreads();
    if (t < 32) {
        float s = 0;
        for (int l = 0; l < 64; ++l) s += red[l][t];
        part_vs[((size_t)bn * 8 + chunk) * 32 + t] = s;
    }
}

// kv_final: also emit kvT bf16 [e][d] for the epilogue's MFMA B-operand
__global__ __launch_bounds__(256) void kv_final(const float* __restrict__ part_kv, const float* __restrict__ part_ks,
                                                const float* __restrict__ part_vs, float* __restrict__ kv_fin,
                                                u16* __restrict__ kvT_bf, float* __restrict__ kmean,
                                                float* __restrict__ vmean) {
    int bn = blockIdx.x;
    int t = threadIdx.x;
    const float* p = part_kv + (size_t)bn * 32 * 1024;
    const float s2c = SCALE_F / (float)N_TOK;
#pragma unroll
    for (int i = 0; i < 4; ++i) {
        int sl = t + i * 256;          // sl = d*32 + e
        float s = 0;
        for (int c = 0; c < 32; ++c) s += p[(size_t)c * 1024 + sl];
        float val = s * s2c;
        kv_fin[(size_t)bn * 1024 + sl] = val;
        int d = sl >> 5, e = sl & 31;
        kvT_bf[(size_t)bn * 1024 + e * 32 + d] = f2bf(val);
    }
    if (t < 32) {
        float s = 0, sv = 0;
        for (int c = 0; c < 8; ++c) {
            s  += part_ks[((size_t)bn * 8 + c) * 32 + t];
            sv += part_vs[((size_t)bn * 8 + c) * 32 + t];
        }
        kmean[bn * 32 + t] = s * (1.f / (float)N_TOK);
        vmean[bn * 32 + t] = sv * (1.f / (float)N_TOK);
    }
}

// ---------------- attention epilogue, MFMA matvec -> resnT[b][l][c] bf16 ----------------
// Per wave: 64 tokens. Phase1 (lane=token): elu,z,theta in fp32 -> bf16 A-tile in LDS.
// Phase2: 8x mfma_16x16x32 vs kv B-tile. Phase3: C-frags -> LDS. Phase4 (lane=token): finish.
__global__ __launch_bounds__(256) void attn_epilogue(const float* __restrict__ qkvo, const float* __restrict__ sinT,
                                                     const float* __restrict__ cosT, const u16* __restrict__ kvT_bf,
                                                     const float* __restrict__ kmean, const float* __restrict__ vmean,
                                                     const u16* __restrict__ lepe, u16* __restrict__ resnT) {
    int lt = blockIdx.x, bn = blockIdx.y;
    int b = bn >> 3, n = bn & 7;
    const float* qp = qkvo + ((size_t)b * 1024 + n * HD) * N_TOK;
    const float* op = qkvo + ((size_t)b * 1024 + 768 + n * HD) * N_TOK;
    const u16* lp = lepe + ((size_t)b * C_DIM + n * HD) * N_TOK;

    __shared__ u16 kvb[32 * 40];            // kv^T [e][d] bf16, stride 40
    __shared__ float kml[32], vml[32];
    __shared__ u16 Atile[4][64 * 40];       // per-wave q' bf16 [tok][d], stride 40
    __shared__ float Rtile[4][64 * 36];     // per-wave res f32 [tok][e], stride 36

    int t = threadIdx.x;
    int w = t >> 6, lane = t & 63;

    if (t < 128) {
        int e = t >> 2, d0 = (t & 3) * 8;
        *(uint4*)(kvb + e * 40 + d0) = *(const uint4*)(kvT_bf + (size_t)bn * 1024 + e * 32 + d0);
    }
    if (t < 32) { kml[t] = kmean[bn * 32 + t]; vml[t] = vmean[bn * 32 + t]; }
    __syncthreads();

    int token = lt * 256 + w * 64 + lane;

    // phase 1: q' in fp32, pack to bf16 A-tile
    float qv[32];
    float z = 0.f;
#pragma unroll
    for (int d = 0; d < 32; ++d) {
        float x_ = qp[(size_t)d * N_TOK + token];
        float e_ = x_ > 0.f ? x_ + 1.f : __expf(x_);
        qv[d] = e_;
        z += e_ * kml[d];
    }
    z *= SCALE_F;
#pragma unroll
    for (int p = 0; p < 16; ++p) {
        float se = sinT[(size_t)(2 * p) * N_TOK + token];
        float so = sinT[(size_t)(2 * p + 1) * N_TOK + token];
        float ce = cosT[(size_t)(2 * p) * N_TOK + token];
        float co = cosT[(size_t)(2 * p + 1) * N_TOK + token];
        float a = qv[2 * p], bb = qv[2 * p + 1];
        qv[2 * p]     = a * ce - bb * se;
        qv[2 * p + 1] = bb * co + a * so;
    }
    float mult = 1.f + 1.f / (z + 1e-6f);

    u16* Aw = Atile[w];
#pragma unroll
    for (int j4 = 0; j4 < 4; ++j4) {
        uint4 u;
        u.x = (u32)f2bf(qv[8 * j4 + 0]) | ((u32)f2bf(qv[8 * j4 + 1]) << 16);
        u.y = (u32)f2bf(qv[8 * j4 + 2]) | ((u32)f2bf(qv[8 * j4 + 3]) << 16);
        u.z = (u32)f2bf(qv[8 * j4 + 4]) | ((u32)f2bf(qv[8 * j4 + 5]) << 16);
        u.w = (u32)f2bf(qv[8 * j4 + 6]) | ((u32)f2bf(qv[8 * j4 + 7]) << 16);
        *(uint4*)(Aw + lane * 40 + j4 * 8) = u;
    }
    __syncthreads();

    // phase 2+3: MFMA and scatter to res tile
    int fr = lane & 15, kg = lane >> 4;
    bf16x8 af[4], bfr[2];
#pragma unroll
    for (int i = 0; i < 4; ++i)
        af[i] = *(const bf16x8*)(Aw + (i * 16 + fr) * 40 + kg * 8);
#pragma unroll
    for (int jj = 0; jj < 2; ++jj)
        bfr[jj] = *(const bf16x8*)(kvb + (jj * 16 + fr) * 40 + kg * 8);

    float* Rw = Rtile[w];
    f32x4 zero = {0.f, 0.f, 0.f, 0.f};
#pragma unroll
    for (int i = 0; i < 4; ++i)
#pragma unroll
        for (int jj = 0; jj < 2; ++jj) {
            f32x4 acc = __builtin_amdgcn_mfma_f32_16x16x32_bf16(af[i], bfr[jj], zero, 0, 0, 0);
#pragma unroll
            for (int r = 0; r < 4; ++r)
                Rw[(i * 16 + kg * 4 + r) * 36 + jj * 16 + fr] = acc[r];
        }
    __syncthreads();

    // phase 4: finish per token
    float res[32];
#pragma unroll
    for (int j = 0; j < 8; ++j) {
        f32x4 vr = *(const f32x4*)(Rw + lane * 36 + j * 4);
        res[4 * j] = vr[0]; res[4 * j + 1] = vr[1]; res[4 * j + 2] = vr[2]; res[4 * j + 3] = vr[3];
    }

    u16* dst0 = resnT + ((size_t)b * N_TOK + token) * C_DIM + n * HD;
#pragma unroll
    for (int g = 0; g < 4; ++g) {
        float vv[8];
#pragma unroll
        for (int e2 = 0; e2 < 8; ++e2) {
            int ee = g * 8 + e2;
            float lx = __uint_as_float((u32)lp[(size_t)ee * N_TOK + token] << 16);
            float ov = op[(size_t)ee * N_TOK + token];
            float rx = res[ee] * mult - z * vml[ee];
            vv[e2] = (rx + lx) * ov;
        }
        uint4 u;
        u.x = (u32)f2bf(vv[0]) | ((u32)f2bf(vv[1]) << 16);
        u.y = (u32)f2bf(vv[2]) | ((u32)f2bf(vv[3]) << 16);
        u.z = (u32)f2bf(vv[4]) | ((u32)f2bf(vv[5]) << 16);
        u.w = (u32)f2bf(vv[6]) | ((u32)f2bf(vv[7]) << 16);
        ((uint4*)(dst0 + g * 8))[0] = u;
    }
}

extern "C" void kernel_launch(void* const* d_in, const int* in_sizes, int n_in,
                              void* d_out, int out_size, void* d_ws, size_t ws_size,
                              hipStream_t stream) {
    const float* x      = (const float*)d_in[0];
    const float* sinp   = (const float*)d_in[1];
    const float* cosp   = (const float*)d_in[2];
    const float* w_qkvo = (const float*)d_in[3];
    const float* b_qkvo = (const float*)d_in[4];
    const float* w_lepe = (const float*)d_in[5];
    const float* b_lepe = (const float*)d_in[6];
    const float* w_proj = (const float*)d_in[7];
    const float* b_proj = (const float*)d_in[8];

    char* ws = (char*)d_ws;
    size_t off = 0;
    auto alloc = [&](size_t bytes) { size_t o = off; off = (off + bytes + 255) & ~(size_t)255; return o; };
    u16*   wbf     = (u16*)(ws + alloc((size_t)1024 * 256 * 2));
    u16*   wpbf    = (u16*)(ws + alloc((size_t)256 * 256 * 2));
    u16*   xT      = (u16*)(ws + alloc((size_t)8 * 4096 * 256 * 2));
    float* qkvo    = (float*)(ws + alloc((size_t)8 * 1024 * 4096 * 4));
    u16*   lepe    = (u16*)(ws + alloc((size_t)8 * 256 * 4096 * 2));
    u16*   resnT   = (u16*)(ws + alloc((size_t)8 * 4096 * 256 * 2));
    float* part_kv = (float*)(ws + alloc((size_t)64 * 32 * 1024 * 4));
    float* part_ks = (float*)(ws + alloc((size_t)64 * 8 * 32 * 4));
    float* part_vs = (float*)(ws + alloc((size_t)64 * 8 * 32 * 4));
    float* kv_fin  = (float*)(ws + alloc((size_t)64 * 1024 * 4));
    u16*   kvT_bf  = (u16*)(ws + alloc((size_t)64 * 1024 * 2));
    float* kmean   = (float*)(ws + alloc((size_t)64 * 32 * 4));
    float* vmean   = (float*)(ws + alloc((size_t)64 * 32 * 4));
    float* sinT    = (float*)(ws + alloc((size_t)32 * 4096 * 4));
    float* cosT    = (float*)(ws + alloc((size_t)32 * 4096 * 4));
    if (off > ws_size) return;  // insufficient workspace -> loud validation failure

    conv_w<<<dim3(1024), dim3(256), 0, stream>>>(w_qkvo, w_proj, wbf, wpbf);
    transpose_sc<<<dim3(64, 2), dim3(256), 0, stream>>>(sinp, cosp, sinT, cosT);
    transpose_x<<<dim3(128, 8, 8), dim3(256), 0, stream>>>(x, xT);
    gemm_bt<<<dim3(32, 8, 8), dim3(256), 0, stream>>>(wbf, xT, b_qkvo, qkvo, 1024, 4096, 256);
    lepe_conv<<<dim3(4, 256, 8), dim3(256), 0, stream>>>(qkvo, w_lepe, b_lepe, lepe);
    kv_reduce<<<dim3(8, 64), dim3(256), 0, stream>>>(qkvo, sinT, cosT, part_kv, part_ks, part_vs);
    kv_final<<<dim3(64), dim3(256), 0, stream>>>(part_kv, part_ks, part_vs, kv_fin, kvT_bf, kmean, vmean);
    attn_epilogue<<<dim3(16, 64), dim3(256), 0, stream>>>(qkvo, sinT, cosT, kvT_bf, kmean, vmean, lepe, resnT);
    gemm_bt<<<dim3(32, 2, 8), dim3(256), 0, stream>>>(wpbf, resnT, b_proj, (float*)d_out, 256, 4096, 256);
}